// Round 8
// baseline (64.626 us; speedup 1.0000x reference)
//
#include <hip/hip_runtime.h>

// Problem constants (from reference)
#define NB 4
#define S_OUT 32                                  // 128 / 4 (two 2x pools fused)
#define NC 64
#define OUT_CELLS (NB * S_OUT * S_OUT * S_OUT)    // 131072
#define OUT_ELEMS (OUT_CELLS * NC)                // 8388608 floats
#define NGROUPS (OUT_CELLS / 4)                   // 32768 (4 cells per wave)
#define CAP 16                                    // slots per cell (lambda=3.8, P(n>16)~7e-7)
#define OVF_CAP 65536
#define GATHER_BLOCKS 2048
#define NWAVES (GATHER_BLOCKS * 4)                // 8192 waves -> 4 groups each

typedef float floatx4 __attribute__((ext_vector_type(4)));   // native vec for nt-store

// ---------- gather path ----------

__global__ void fill_kernel(const int4* __restrict__ coors,
                            int* __restrict__ cnt,
                            int* __restrict__ list,
                            int* __restrict__ ovf_cnt,
                            int* __restrict__ ovf,
                            int n_pts) {
    int p = blockIdx.x * blockDim.x + threadIdx.x;
    if (p >= n_pts) return;
    int4 co = coors[p];
    int cell = ((co.x * S_OUT + (co.y >> 2)) * S_OUT + (co.z >> 2)) * S_OUT + (co.w >> 2);
    int slot = atomicAdd(&cnt[cell], 1);
    if (slot < CAP) {
        list[cell * CAP + slot] = p;
    } else {
        int o = atomicAdd(ovf_cnt, 1);
        if (o < OVF_CAP) ovf[o] = p;   // owner group folds these in gather
    }
}

// 4 cells per wave (16-lane group per cell, lane holds channel quad).
// Each wave owns exactly 4 groups: g_i = wid + i*NWAVES. All metadata issued
// up front; feature rows register-double-buffered: rows(g_{i+1}) issued
// BEFORE consuming rows(g_i), so consumption waits with counted vmcnt while
// the next group's 8 row-loads stay in flight.
__global__ __launch_bounds__(256) void gather_kernel(
        const float* __restrict__ features,
        const int4* __restrict__ coors,
        const int* __restrict__ cnt,
        const int* __restrict__ list,
        const int* __restrict__ ovf_cnt,
        const int* __restrict__ ovf,
        float* __restrict__ out) {
    const int lane  = threadIdx.x & 63;
    const int wid   = (blockIdx.x * blockDim.x + threadIdx.x) >> 6;
    const int cl    = (lane & 15) << 2;    // channel quad base
    const int sbase = lane & 48;           // group's slot base lane
    const int qsel  = lane >> 4;           // group index 0..3

    // ---- all 4 groups' metadata issued back-to-back ----
#define META(i) \
    const int g##i = wid + (i) * NWAVES; \
    int n##i = cnt[(g##i << 2) + qsel]; \
    int pl##i = list[((size_t)g##i << 6) + lane];
    META(0) META(1) META(2) META(3)
#undef META

    float4 a0, a1, a2, a3, a4, a5, a6, a7;   // buffer A
    float4 b0, b1, b2, b3, b4, b5, b6, b7;   // buffer B

    // issue 8 row-loads for group i into buffer regs R0..R7.
    // invalid slots (s >= m) -> row 0 (cache-hot dummy); list slots beyond n
    // hold poison/stale ids and must never be dereferenced raw.
#define ISSUE(i, R0,R1,R2,R3,R4,R5,R6,R7) \
    { \
        int m_ = n##i < CAP ? n##i : CAP; \
        int p_; \
        p_ = __shfl(pl##i, sbase + 0); R0 = *(const float4*)(features + (size_t)(0 < m_ ? p_ : 0) * NC + cl); \
        p_ = __shfl(pl##i, sbase + 1); R1 = *(const float4*)(features + (size_t)(1 < m_ ? p_ : 0) * NC + cl); \
        p_ = __shfl(pl##i, sbase + 2); R2 = *(const float4*)(features + (size_t)(2 < m_ ? p_ : 0) * NC + cl); \
        p_ = __shfl(pl##i, sbase + 3); R3 = *(const float4*)(features + (size_t)(3 < m_ ? p_ : 0) * NC + cl); \
        p_ = __shfl(pl##i, sbase + 4); R4 = *(const float4*)(features + (size_t)(4 < m_ ? p_ : 0) * NC + cl); \
        p_ = __shfl(pl##i, sbase + 5); R5 = *(const float4*)(features + (size_t)(5 < m_ ? p_ : 0) * NC + cl); \
        p_ = __shfl(pl##i, sbase + 6); R6 = *(const float4*)(features + (size_t)(6 < m_ ? p_ : 0) * NC + cl); \
        p_ = __shfl(pl##i, sbase + 7); R7 = *(const float4*)(features + (size_t)(7 < m_ ? p_ : 0) * NC + cl); \
    }

#define FM(ACC, F) \
    ACC.x = fmaxf(ACC.x, F.x); ACC.y = fmaxf(ACC.y, F.y); \
    ACC.z = fmaxf(ACC.z, F.z); ACC.w = fmaxf(ACC.w, F.w);

    // consume buffer for group i, fold tail/overflow, store output row.
#define CONSUME(i, R0,R1,R2,R3,R4,R5,R6,R7) \
    { \
        int m_ = n##i < CAP ? n##i : CAP; \
        float4 acc = make_float4(-INFINITY, -INFINITY, -INFINITY, -INFINITY); \
        if (0 < m_) { FM(acc, R0) } \
        if (1 < m_) { FM(acc, R1) } \
        if (2 < m_) { FM(acc, R2) } \
        if (3 < m_) { FM(acc, R3) } \
        if (4 < m_) { FM(acc, R4) } \
        if (5 < m_) { FM(acc, R5) } \
        if (6 < m_) { FM(acc, R6) } \
        if (7 < m_) { FM(acc, R7) } \
        if (__builtin_expect(m_ > 8, 0)) { \
            for (int s_ = 8; s_ < m_; ++s_) { \
                int p_ = __shfl(pl##i, sbase + s_); \
                const float4 f_ = *(const float4*)(features + (size_t)p_ * NC + cl); \
                FM(acc, f_) \
            } \
        } \
        if (__builtin_expect(__any(n##i > CAP), 0)) { \
            int mycell_ = (g##i << 2) + qsel; \
            int novf_ = *ovf_cnt; \
            if (novf_ > OVF_CAP) novf_ = OVF_CAP; \
            for (int t_ = 0; t_ < novf_; ++t_) { \
                int p_ = ovf[t_]; \
                int4 co_ = coors[p_]; \
                int cellp_ = ((co_.x * S_OUT + (co_.y >> 2)) * S_OUT + (co_.z >> 2)) * S_OUT + (co_.w >> 2); \
                if (n##i > CAP && cellp_ == mycell_) { \
                    const float4 f_ = *(const float4*)(features + (size_t)p_ * NC + cl); \
                    FM(acc, f_) \
                } \
            } \
        } \
        if (n##i == 0) acc = make_float4(0.f, 0.f, 0.f, 0.f); \
        floatx4 av_ = { acc.x, acc.y, acc.z, acc.w }; \
        __builtin_nontemporal_store(av_, (floatx4*)(out + ((size_t)g##i << 8) + (size_t)lane * 4)); \
    }

    // software pipeline: issue next buffer before consuming current
    ISSUE(0, a0,a1,a2,a3,a4,a5,a6,a7)
    ISSUE(1, b0,b1,b2,b3,b4,b5,b6,b7)
    CONSUME(0, a0,a1,a2,a3,a4,a5,a6,a7)
    ISSUE(2, a0,a1,a2,a3,a4,a5,a6,a7)
    CONSUME(1, b0,b1,b2,b3,b4,b5,b6,b7)
    ISSUE(3, b0,b1,b2,b3,b4,b5,b6,b7)
    CONSUME(2, a0,a1,a2,a3,a4,a5,a6,a7)
    CONSUME(3, b0,b1,b2,b3,b4,b5,b6,b7)

#undef ISSUE
#undef CONSUME
#undef FM
}

// ---------- fallback path (R1's working atomicMax scatter) ----------

__device__ __forceinline__ unsigned flip_f(float f) {
    unsigned u = __float_as_uint(f);
    return (u & 0x80000000u) ? ~u : (u | 0x80000000u);
}
__device__ __forceinline__ float unflip_f(unsigned u) {
    unsigned v = (u & 0x80000000u) ? (u & 0x7FFFFFFFu) : ~u;
    return __uint_as_float(v);
}

__global__ void init_kernel(uint4* __restrict__ out4, int n4) {
    int i = blockIdx.x * blockDim.x + threadIdx.x;
    int stride = gridDim.x * blockDim.x;
    uint4 z = make_uint4(0u, 0u, 0u, 0u);
    for (; i < n4; i += stride) out4[i] = z;
}

__global__ void scatter_kernel(const float* __restrict__ features,
                               const int4* __restrict__ coors,
                               unsigned* __restrict__ acc, int n_pts) {
    int gid = blockIdx.x * blockDim.x + threadIdx.x;
    int p = gid >> 6;
    int c = threadIdx.x & 63;
    if (p >= n_pts) return;
    int4 co = coors[p];
    int cell = ((co.x * S_OUT + (co.y >> 2)) * S_OUT + (co.z >> 2)) * S_OUT + (co.w >> 2);
    atomicMax(acc + (size_t)cell * NC + c, flip_f(features[(size_t)p * NC + c]));
}

__global__ void finalize_kernel(unsigned* __restrict__ acc, int n) {
    int i = blockIdx.x * blockDim.x + threadIdx.x;
    int stride = gridDim.x * blockDim.x;
    for (; i < n; i += stride) {
        unsigned u = acc[i];
        ((float*)acc)[i] = (u == 0u) ? 0.0f : unflip_f(u);
    }
}

extern "C" void kernel_launch(void* const* d_in, const int* in_sizes, int n_in,
                              void* d_out, int out_size, void* d_ws, size_t ws_size,
                              hipStream_t stream) {
    const float* features = (const float*)d_in[0];
    const int4*  coors    = (const int4*)d_in[1];
    int n_pts = in_sizes[0] / NC;   // 500000

    // workspace layout
    const size_t off_cnt  = 0;
    const size_t cnt_b    = (size_t)OUT_CELLS * 4;             // 524288
    const size_t off_ovfc = cnt_b;                             // 4B counter
    const size_t off_ovf  = off_ovfc + 256;
    const size_t off_list = off_ovf + (size_t)OVF_CAP * 4;
    const size_t need     = off_list + (size_t)OUT_CELLS * CAP * 4;   // ~9 MB

    if (ws_size >= need) {
        char* ws = (char*)d_ws;
        int* cnt     = (int*)(ws + off_cnt);
        int* ovf_cnt = (int*)(ws + off_ovfc);
        int* ovf     = (int*)(ws + off_ovf);
        int* list    = (int*)(ws + off_list);
        float* out   = (float*)d_out;

        // zero counters (cnt region + overflow counter)
        (void)hipMemsetAsync(ws, 0, off_ovfc + 4, stream);

        // build per-cell point lists
        {
            int block = 256;
            int grid = (n_pts + block - 1) / block;
            fill_kernel<<<grid, block, 0, stream>>>(coors, cnt, list, ovf_cnt, ovf, n_pts);
        }
        // gather max: 4 groups per wave, register-double-buffered pipeline
        gather_kernel<<<GATHER_BLOCKS, 256, 0, stream>>>(features, coors, cnt, list,
                                                         ovf_cnt, ovf, out);
    } else {
        // fallback: R1 atomic scatter path
        unsigned* acc = (unsigned*)d_out;
        init_kernel<<<2048, 256, 0, stream>>>((uint4*)d_out, OUT_ELEMS / 4);
        int grid = (n_pts * 64 + 255) / 256;
        scatter_kernel<<<grid, 256, 0, stream>>>(features, coors, acc, n_pts);
        finalize_kernel<<<2048, 256, 0, stream>>>(acc, OUT_ELEMS);
    }
}

// Round 9
// 63.274 us; speedup vs baseline: 1.0214x; 1.0214x over previous
//
#include <hip/hip_runtime.h>

// Problem constants (from reference)
#define NB 4
#define S_OUT 32                                  // 128 / 4 (two 2x pools fused)
#define NC 64
#define OUT_CELLS (NB * S_OUT * S_OUT * S_OUT)    // 131072
#define OUT_ELEMS (OUT_CELLS * NC)                // 8388608 floats
#define NGROUPS (OUT_CELLS / 4)                   // 32768 (4 cells per wave)
#define CAP 16                                    // slots per cell (lambda=3.8, P(n>16)~7e-7)
#define OVF_CAP 65536

typedef float floatx4 __attribute__((ext_vector_type(4)));   // native vec for nt-store

// ---------- gather path ----------

__global__ void fill_kernel(const int4* __restrict__ coors,
                            int* __restrict__ cnt,
                            int* __restrict__ list,
                            int* __restrict__ ovf_cnt,
                            int* __restrict__ ovf,
                            int n_pts) {
    int p = blockIdx.x * blockDim.x + threadIdx.x;
    if (p >= n_pts) return;
    int4 co = coors[p];
    int cell = ((co.x * S_OUT + (co.y >> 2)) * S_OUT + (co.z >> 2)) * S_OUT + (co.w >> 2);
    int slot = atomicAdd(&cnt[cell], 1);
    if (slot < CAP) {
        list[cell * CAP + slot] = p;
    } else {
        int o = atomicAdd(ovf_cnt, 1);
        if (o < OVF_CAP) ovf[o] = p;   // owner group folds these in gather
    }
}

// 4 cells per wave; 16-lane group q = lane>>4 owns cell (g*4+q); lane holds
// channel quad cl=(lane&15)*4. Grid-stride with next-iteration metadata
// prefetch. R9 change: the 8 unrolled slot-loads are EXEC-MASKED per lane
// (if s<m) instead of dummy-redirected to row 0 -> invalid lanes make no
// memory requests, halving fetched segments.
__global__ __launch_bounds__(256) void gather_kernel(
        const float* __restrict__ features,
        const int4* __restrict__ coors,
        const int* __restrict__ cnt,
        const int* __restrict__ list,
        const int* __restrict__ ovf_cnt,
        const int* __restrict__ ovf,
        float* __restrict__ out) {
    const int lane  = threadIdx.x & 63;
    const int wid   = (blockIdx.x * blockDim.x + threadIdx.x) >> 6;
    const int nw    = (gridDim.x * blockDim.x) >> 6;
    const int cl    = (lane & 15) << 2;    // channel quad base
    const int sbase = lane & 48;           // group's slot base lane
    const int qsel  = lane >> 4;           // group index 0..3

    int g = wid;
    if (g >= NGROUPS) return;

    // prefetch first group's metadata
    int n_pf  = cnt[(g << 2) + qsel];
    int pl_pf = list[((size_t)g << 6) + lane];   // 4 cells x 16 slots = 64 dwords

    while (true) {
        int n  = n_pf;
        int pl = pl_pf;
        int gn = g + nw;
        if (gn < NGROUPS) {                       // prefetch next iteration
            n_pf  = cnt[(gn << 2) + qsel];
            pl_pf = list[((size_t)gn << 6) + lane];
        }

        int m = n < CAP ? n : CAP;
        float4 acc = make_float4(-INFINITY, -INFINITY, -INFINITY, -INFINITY);

        #pragma unroll
        for (int s = 0; s < 8; ++s) {
            int p = __shfl(pl, sbase + s);
            if (s < m) {                          // exec-masked: inactive lanes
                const float4 f = *(const float4*)(features + (size_t)p * NC + cl);
                acc.x = fmaxf(acc.x, f.x); acc.y = fmaxf(acc.y, f.y);
                acc.z = fmaxf(acc.z, f.z); acc.w = fmaxf(acc.w, f.w);
            }
        }
        if (m > 8) {                              // uncommon tail (P ~ 1.3%)
            for (int s = 8; s < m; ++s) {
                int p = __shfl(pl, sbase + s);
                const float4 f = *(const float4*)(features + (size_t)p * NC + cl);
                acc.x = fmaxf(acc.x, f.x); acc.y = fmaxf(acc.y, f.y);
                acc.z = fmaxf(acc.z, f.z); acc.w = fmaxf(acc.w, f.w);
            }
        }
        if (__builtin_expect(__any(n > CAP), 0)) {   // owner-side overflow fold
            int mycell = (g << 2) + qsel;
            int novf = *ovf_cnt;
            if (novf > OVF_CAP) novf = OVF_CAP;
            for (int i = 0; i < novf; ++i) {
                int p = ovf[i];                   // broadcast load
                int4 co = coors[p];
                int cellp = ((co.x * S_OUT + (co.y >> 2)) * S_OUT + (co.z >> 2)) * S_OUT + (co.w >> 2);
                if (n > CAP && cellp == mycell) {
                    const float4 f = *(const float4*)(features + (size_t)p * NC + cl);
                    acc.x = fmaxf(acc.x, f.x); acc.y = fmaxf(acc.y, f.y);
                    acc.z = fmaxf(acc.z, f.z); acc.w = fmaxf(acc.w, f.w);
                }
            }
        }
        if (n == 0) acc = make_float4(0.f, 0.f, 0.f, 0.f);
        floatx4 accv = { acc.x, acc.y, acc.z, acc.w };
        __builtin_nontemporal_store(accv, (floatx4*)(out + ((size_t)g << 8) + (size_t)lane * 4));

        if (gn >= NGROUPS) break;
        g = gn;
    }
}

// ---------- fallback path (R1's working atomicMax scatter) ----------

__device__ __forceinline__ unsigned flip_f(float f) {
    unsigned u = __float_as_uint(f);
    return (u & 0x80000000u) ? ~u : (u | 0x80000000u);
}
__device__ __forceinline__ float unflip_f(unsigned u) {
    unsigned v = (u & 0x80000000u) ? (u & 0x7FFFFFFFu) : ~u;
    return __uint_as_float(v);
}

__global__ void init_kernel(uint4* __restrict__ out4, int n4) {
    int i = blockIdx.x * blockDim.x + threadIdx.x;
    int stride = gridDim.x * blockDim.x;
    uint4 z = make_uint4(0u, 0u, 0u, 0u);
    for (; i < n4; i += stride) out4[i] = z;
}

__global__ void scatter_kernel(const float* __restrict__ features,
                               const int4* __restrict__ coors,
                               unsigned* __restrict__ acc, int n_pts) {
    int gid = blockIdx.x * blockDim.x + threadIdx.x;
    int p = gid >> 6;
    int c = threadIdx.x & 63;
    if (p >= n_pts) return;
    int4 co = coors[p];
    int cell = ((co.x * S_OUT + (co.y >> 2)) * S_OUT + (co.z >> 2)) * S_OUT + (co.w >> 2);
    atomicMax(acc + (size_t)cell * NC + c, flip_f(features[(size_t)p * NC + c]));
}

__global__ void finalize_kernel(unsigned* __restrict__ acc, int n) {
    int i = blockIdx.x * blockDim.x + threadIdx.x;
    int stride = gridDim.x * blockDim.x;
    for (; i < n; i += stride) {
        unsigned u = acc[i];
        ((float*)acc)[i] = (u == 0u) ? 0.0f : unflip_f(u);
    }
}

extern "C" void kernel_launch(void* const* d_in, const int* in_sizes, int n_in,
                              void* d_out, int out_size, void* d_ws, size_t ws_size,
                              hipStream_t stream) {
    const float* features = (const float*)d_in[0];
    const int4*  coors    = (const int4*)d_in[1];
    int n_pts = in_sizes[0] / NC;   // 500000

    // workspace layout
    const size_t off_cnt  = 0;
    const size_t cnt_b    = (size_t)OUT_CELLS * 4;             // 524288
    const size_t off_ovfc = cnt_b;                             // 4B counter
    const size_t off_ovf  = off_ovfc + 256;
    const size_t off_list = off_ovf + (size_t)OVF_CAP * 4;
    const size_t need     = off_list + (size_t)OUT_CELLS * CAP * 4;   // ~9 MB

    if (ws_size >= need) {
        char* ws = (char*)d_ws;
        int* cnt     = (int*)(ws + off_cnt);
        int* ovf_cnt = (int*)(ws + off_ovfc);
        int* ovf     = (int*)(ws + off_ovf);
        int* list    = (int*)(ws + off_list);
        float* out   = (float*)d_out;

        // zero counters (cnt region + overflow counter)
        (void)hipMemsetAsync(ws, 0, off_ovfc + 4, stream);

        // build per-cell point lists
        {
            int block = 256;
            int grid = (n_pts + block - 1) / block;
            fill_kernel<<<grid, block, 0, stream>>>(coors, cnt, list, ovf_cnt, ovf, n_pts);
        }
        // gather max (+ owner-side overflow fold): 4 cells/wave, masked loads
        {
            int block = 256;
            int grid = 2048;    // 8192 waves, 4 groups each
            gather_kernel<<<grid, block, 0, stream>>>(features, coors, cnt, list,
                                                      ovf_cnt, ovf, out);
        }
    } else {
        // fallback: R1 atomic scatter path
        unsigned* acc = (unsigned*)d_out;
        init_kernel<<<2048, 256, 0, stream>>>((uint4*)d_out, OUT_ELEMS / 4);
        int grid = (n_pts * 64 + 255) / 256;
        scatter_kernel<<<grid, 256, 0, stream>>>(features, coors, acc, n_pts);
        finalize_kernel<<<2048, 256, 0, stream>>>(acc, OUT_ELEMS);
    }
}

// Round 10
// 62.104 us; speedup vs baseline: 1.0406x; 1.0188x over previous
//
#include <hip/hip_runtime.h>

// Problem constants (from reference)
#define NB 4
#define S_OUT 32                                  // 128 / 4 (two 2x pools fused)
#define NC 64
#define OUT_CELLS (NB * S_OUT * S_OUT * S_OUT)    // 131072
#define OUT_ELEMS (OUT_CELLS * NC)                // 8388608 floats
#define NGROUPS (OUT_CELLS / 4)                   // 32768 (4 cells per wave)
#define CAP 16                                    // slots per cell (lambda=3.8, P(n>16)~7e-7)
#define OVF_CAP 65536

typedef float floatx4 __attribute__((ext_vector_type(4)));   // native vec for nt-store

// ---------- gather path ----------

// Zeroes cnt[OUT_CELLS] + ovf counter. Replaces hipMemsetAsync (rocclr
// fillBufferAligned showed ~72us/dispatch in profiles - untrusted path).
__global__ __launch_bounds__(256) void zero_kernel(uint4* __restrict__ cnt4,
                                                   int* __restrict__ ovf_cnt) {
    int i = blockIdx.x * blockDim.x + threadIdx.x;
    // OUT_CELLS*4 bytes = 32768 uint4s; grid exactly covers it
    cnt4[i] = make_uint4(0u, 0u, 0u, 0u);
    if (i == 0) *ovf_cnt = 0;
}

__global__ void fill_kernel(const int4* __restrict__ coors,
                            int* __restrict__ cnt,
                            int* __restrict__ list,
                            int* __restrict__ ovf_cnt,
                            int* __restrict__ ovf,
                            int n_pts) {
    int p = blockIdx.x * blockDim.x + threadIdx.x;
    if (p >= n_pts) return;
    int4 co = coors[p];
    int cell = ((co.x * S_OUT + (co.y >> 2)) * S_OUT + (co.z >> 2)) * S_OUT + (co.w >> 2);
    int slot = atomicAdd(&cnt[cell], 1);
    if (slot < CAP) {
        list[cell * CAP + slot] = p;
    } else {
        int o = atomicAdd(ovf_cnt, 1);
        if (o < OVF_CAP) ovf[o] = p;   // owner group folds these in gather
    }
}

// 4 cells per wave; 16-lane group q = lane>>4 owns cell (g*4+q); lane holds
// channel quad cl=(lane&15)*4. Grid-stride with next-iteration metadata
// prefetch; exec-masked slot loads (R9).
__global__ __launch_bounds__(256) void gather_kernel(
        const float* __restrict__ features,
        const int4* __restrict__ coors,
        const int* __restrict__ cnt,
        const int* __restrict__ list,
        const int* __restrict__ ovf_cnt,
        const int* __restrict__ ovf,
        float* __restrict__ out) {
    const int lane  = threadIdx.x & 63;
    const int wid   = (blockIdx.x * blockDim.x + threadIdx.x) >> 6;
    const int nw    = (gridDim.x * blockDim.x) >> 6;
    const int cl    = (lane & 15) << 2;    // channel quad base
    const int sbase = lane & 48;           // group's slot base lane
    const int qsel  = lane >> 4;           // group index 0..3

    int g = wid;
    if (g >= NGROUPS) return;

    // prefetch first group's metadata
    int n_pf  = cnt[(g << 2) + qsel];
    int pl_pf = list[((size_t)g << 6) + lane];   // 4 cells x 16 slots = 64 dwords

    while (true) {
        int n  = n_pf;
        int pl = pl_pf;
        int gn = g + nw;
        if (gn < NGROUPS) {                       // prefetch next iteration
            n_pf  = cnt[(gn << 2) + qsel];
            pl_pf = list[((size_t)gn << 6) + lane];
        }

        int m = n < CAP ? n : CAP;
        float4 acc = make_float4(-INFINITY, -INFINITY, -INFINITY, -INFINITY);

        #pragma unroll
        for (int s = 0; s < 8; ++s) {
            int p = __shfl(pl, sbase + s);
            if (s < m) {                          // exec-masked: inactive lanes
                const float4 f = *(const float4*)(features + (size_t)p * NC + cl);
                acc.x = fmaxf(acc.x, f.x); acc.y = fmaxf(acc.y, f.y);
                acc.z = fmaxf(acc.z, f.z); acc.w = fmaxf(acc.w, f.w);
            }
        }
        if (m > 8) {                              // uncommon tail (P ~ 1.3%)
            for (int s = 8; s < m; ++s) {
                int p = __shfl(pl, sbase + s);
                const float4 f = *(const float4*)(features + (size_t)p * NC + cl);
                acc.x = fmaxf(acc.x, f.x); acc.y = fmaxf(acc.y, f.y);
                acc.z = fmaxf(acc.z, f.z); acc.w = fmaxf(acc.w, f.w);
            }
        }
        if (__builtin_expect(__any(n > CAP), 0)) {   // owner-side overflow fold
            int mycell = (g << 2) + qsel;
            int novf = *ovf_cnt;
            if (novf > OVF_CAP) novf = OVF_CAP;
            for (int i = 0; i < novf; ++i) {
                int p = ovf[i];                   // broadcast load
                int4 co = coors[p];
                int cellp = ((co.x * S_OUT + (co.y >> 2)) * S_OUT + (co.z >> 2)) * S_OUT + (co.w >> 2);
                if (n > CAP && cellp == mycell) {
                    const float4 f = *(const float4*)(features + (size_t)p * NC + cl);
                    acc.x = fmaxf(acc.x, f.x); acc.y = fmaxf(acc.y, f.y);
                    acc.z = fmaxf(acc.z, f.z); acc.w = fmaxf(acc.w, f.w);
                }
            }
        }
        if (n == 0) acc = make_float4(0.f, 0.f, 0.f, 0.f);
        floatx4 accv = { acc.x, acc.y, acc.z, acc.w };
        __builtin_nontemporal_store(accv, (floatx4*)(out + ((size_t)g << 8) + (size_t)lane * 4));

        if (gn >= NGROUPS) break;
        g = gn;
    }
}

// ---------- fallback path (R1's working atomicMax scatter) ----------

__device__ __forceinline__ unsigned flip_f(float f) {
    unsigned u = __float_as_uint(f);
    return (u & 0x80000000u) ? ~u : (u | 0x80000000u);
}
__device__ __forceinline__ float unflip_f(unsigned u) {
    unsigned v = (u & 0x80000000u) ? (u & 0x7FFFFFFFu) : ~u;
    return __uint_as_float(v);
}

__global__ void init_kernel(uint4* __restrict__ out4, int n4) {
    int i = blockIdx.x * blockDim.x + threadIdx.x;
    int stride = gridDim.x * blockDim.x;
    uint4 z = make_uint4(0u, 0u, 0u, 0u);
    for (; i < n4; i += stride) out4[i] = z;
}

__global__ void scatter_kernel(const float* __restrict__ features,
                               const int4* __restrict__ coors,
                               unsigned* __restrict__ acc, int n_pts) {
    int gid = blockIdx.x * blockDim.x + threadIdx.x;
    int p = gid >> 6;
    int c = threadIdx.x & 63;
    if (p >= n_pts) return;
    int4 co = coors[p];
    int cell = ((co.x * S_OUT + (co.y >> 2)) * S_OUT + (co.z >> 2)) * S_OUT + (co.w >> 2);
    atomicMax(acc + (size_t)cell * NC + c, flip_f(features[(size_t)p * NC + c]));
}

__global__ void finalize_kernel(unsigned* __restrict__ acc, int n) {
    int i = blockIdx.x * blockDim.x + threadIdx.x;
    int stride = gridDim.x * blockDim.x;
    for (; i < n; i += stride) {
        unsigned u = acc[i];
        ((float*)acc)[i] = (u == 0u) ? 0.0f : unflip_f(u);
    }
}

extern "C" void kernel_launch(void* const* d_in, const int* in_sizes, int n_in,
                              void* d_out, int out_size, void* d_ws, size_t ws_size,
                              hipStream_t stream) {
    const float* features = (const float*)d_in[0];
    const int4*  coors    = (const int4*)d_in[1];
    int n_pts = in_sizes[0] / NC;   // 500000

    // workspace layout
    const size_t off_cnt  = 0;
    const size_t cnt_b    = (size_t)OUT_CELLS * 4;             // 524288
    const size_t off_ovfc = cnt_b;                             // 4B counter
    const size_t off_ovf  = off_ovfc + 256;
    const size_t off_list = off_ovf + (size_t)OVF_CAP * 4;
    const size_t need     = off_list + (size_t)OUT_CELLS * CAP * 4;   // ~9 MB

    if (ws_size >= need) {
        char* ws = (char*)d_ws;
        int* cnt     = (int*)(ws + off_cnt);
        int* ovf_cnt = (int*)(ws + off_ovfc);
        int* ovf     = (int*)(ws + off_ovf);
        int* list    = (int*)(ws + off_list);
        float* out   = (float*)d_out;

        // zero counters with our own kernel (replaces rocclr fillBufferAligned)
        {
            int n4 = OUT_CELLS * 4 / 16;          // 32768 uint4s
            zero_kernel<<<n4 / 256, 256, 0, stream>>>((uint4*)cnt, ovf_cnt);
        }
        // build per-cell point lists
        {
            int block = 256;
            int grid = (n_pts + block - 1) / block;
            fill_kernel<<<grid, block, 0, stream>>>(coors, cnt, list, ovf_cnt, ovf, n_pts);
        }
        // gather max (+ owner-side overflow fold): 4 cells/wave, masked loads
        {
            int block = 256;
            int grid = 2048;    // 8192 waves, 4 groups each
            gather_kernel<<<grid, block, 0, stream>>>(features, coors, cnt, list,
                                                      ovf_cnt, ovf, out);
        }
    } else {
        // fallback: R1 atomic scatter path
        unsigned* acc = (unsigned*)d_out;
        init_kernel<<<2048, 256, 0, stream>>>((uint4*)d_out, OUT_ELEMS / 4);
        int grid = (n_pts * 64 + 255) / 256;
        scatter_kernel<<<grid, 256, 0, stream>>>(features, coors, acc, n_pts);
        finalize_kernel<<<2048, 256, 0, stream>>>(acc, OUT_ELEMS);
    }
}